// Round 3
// baseline (539.637 us; speedup 1.0000x reference)
//
#include <hip/hip_runtime.h>
#include <stdint.h>
#include <math.h>

// Problem constants (from reference):
#define BB 8
#define CC 32
#define TT 3136      // 56*56
#define KK 9
#define OC 64

#define NEGINF (-3.0e38f)

// ---------------------------------------------------------------------------
// Kernel 1: transposed copies + norms.
//   xnT[b][t][c] = x[b][c][t] * invn  (fp32, for fp32 cosine scan)
//   xfT[b][t][c] = x[b][c][t]         (fp32 raw, for fp64 re-rank + gconv)
//   invn[b][t]   = 1/max(sqrt(sum x^2),1e-12) (fp64, for exact re-rank)
// ---------------------------------------------------------------------------
__global__ __launch_bounds__(256) void norm_kernel(
    const float* __restrict__ x, float* __restrict__ xnT,
    float* __restrict__ xfT, double* __restrict__ invn)
{
    int t = blockIdx.x * 256 + threadIdx.x;
    int b = blockIdx.y;
    if (t >= TT) return;
    const float* xp = x + (size_t)b * CC * TT + t;
    float v[CC];
    double ss = 0.0;
#pragma unroll
    for (int c = 0; c < CC; ++c) {
        v[c] = xp[(size_t)c * TT];
        ss = fma((double)v[c], (double)v[c], ss);
    }
    double inv = 1.0 / fmax(sqrt(ss), 1e-12);
    invn[(size_t)b * TT + t] = inv;
    float invf = (float)inv;
    float* pf = xfT + ((size_t)b * TT + t) * CC;
    float* pn = xnT + ((size_t)b * TT + t) * CC;
#pragma unroll
    for (int c = 0; c < CC; c += 4) {
        *(float4*)(pf + c) = make_float4(v[c], v[c+1], v[c+2], v[c+3]);
        *(float4*)(pn + c) = make_float4(v[c]*invf, v[c+1]*invf, v[c+2]*invf, v[c+3]*invf);
    }
}

// ---------------------------------------------------------------------------
// sorted top-12 (desc) branchless shift-insert; caller guarantees s > val[11]
// ---------------------------------------------------------------------------
__device__ __forceinline__ void insert12(float (&val)[12], int (&ids)[12],
                                         float s, int idx)
{
#pragma unroll
    for (int j = 11; j >= 1; --j) {
        bool up   = s > val[j-1];
        bool here = (s > val[j]) && !up;
        val[j] = up ? val[j-1] : (here ? s   : val[j]);
        ids[j] = up ? ids[j-1] : (here ? idx : ids[j]);
    }
    if (s > val[0]) { val[0] = s; ids[0] = idx; }
}

__device__ __forceinline__ void insert12_u64(uint64_t (&kv)[12], uint64_t k)
{
#pragma unroll
    for (int j = 11; j >= 1; --j) {
        bool up   = k > kv[j-1];
        bool here = (k > kv[j]) && !up;
        kv[j] = up ? kv[j-1] : (here ? k : kv[j]);
    }
    if (k > kv[0]) kv[0] = k;
}

// ---------------------------------------------------------------------------
// scan one LDS tile: JN columns per scanner (stride-8 interleave), 16 (or 8)
// parallel accumulators, then argmax-consume insert passes (wave-merged).
// ---------------------------------------------------------------------------
template<int JN>
__device__ __forceinline__ void scan_tile(
    const float* __restrict__ cols, const float (&rv)[CC],
    float (&val)[12], int (&ids)[12], int q, int t, int s0)
{
    float sc[JN];
#pragma unroll
    for (int j = 0; j < JN; ++j) sc[j] = 0.f;

#pragma unroll
    for (int c = 0; c < CC; c += 4) {
        float rx = rv[c], ry = rv[c+1], rz = rv[c+2], rw = rv[c+3];
#pragma unroll
        for (int j = 0; j < JN; ++j) {
            float4 cv = *(const float4*)(cols + (j*8 + q)*36 + c);
            sc[j] = fmaf(rx, cv.x, sc[j]);
            sc[j] = fmaf(ry, cv.y, sc[j]);
            sc[j] = fmaf(rz, cv.z, sc[j]);
            sc[j] = fmaf(rw, cv.w, sc[j]);
        }
    }
    // mask self
#pragma unroll
    for (int j = 0; j < JN; ++j)
        if (s0 + j*8 + q == t) sc[j] = NEGINF;

    // argmax-consume passes (wave-merged inserts)
    for (int pass = 0; pass < JN; ++pass) {
        float m = sc[0]; int am = 0;
#pragma unroll
        for (int j = 1; j < JN; ++j) {
            bool g = sc[j] > m;
            m  = g ? sc[j] : m;
            am = g ? j : am;
        }
        bool want = m > val[11];
        if (!__any(want)) break;
        if (want) {
            insert12(val, ids, m, s0 + am*8 + q);
#pragma unroll
            for (int j = 0; j < JN; ++j)
                if (am == j) sc[j] = NEGINF;
        }
    }
}

// ---------------------------------------------------------------------------
// Kernel 2: fp32 cosine scan + top-12 + fused merge + fp64 re-rank.
// Block: 256 threads = 32 rows x 8 scanners; 784 blocks.
// LDS: column tile (128 cols x 36 fp32) reused as merge key buffer.
// ---------------------------------------------------------------------------
__global__ __launch_bounds__(256) void topk_kernel(
    const float* __restrict__ xnT, const float* __restrict__ xfT,
    const double* __restrict__ invn, int* __restrict__ idxo)
{
    __shared__ uint64_t mbuf[32 * 97];          // 24832 B
    float* cols = (float*)mbuf;                 // 128*36*4 = 18432 B view

    int tid = threadIdx.x;
    int b   = blockIdx.y;
    int r   = tid >> 3;
    int q   = tid & 7;
    int t   = blockIdx.x * 32 + r;

    // normalized row vector (fp32)
    const float* rowp = xnT + ((size_t)b * TT + t) * CC;
    float rv[CC];
#pragma unroll
    for (int c = 0; c < CC; c += 4) {
        float4 f = *(const float4*)(rowp + c);
        rv[c] = f.x; rv[c+1] = f.y; rv[c+2] = f.z; rv[c+3] = f.w;
    }

    float val[12]; int ids[12];
#pragma unroll
    for (int j = 0; j < 12; ++j) { val[j] = NEGINF; ids[j] = 0x7FFFFFFF; }

    for (int s0 = 0; s0 < TT; s0 += 128) {
        int count = min(128, TT - s0);   // 128 or 64
        __syncthreads();
        for (int f = tid; f < count * 8; f += 256) {
            int col = f >> 3, part = f & 7;
            *(float4*)(cols + col*36 + part*4) =
                *(const float4*)(xnT + ((size_t)b * TT + s0 + col) * CC + part*4);
        }
        __syncthreads();
        if (count == 128) scan_tile<16>(cols, rv, val, ids, q, t, s0);
        else              scan_tile<8> (cols, rv, val, ids, q, t, s0);
    }
    __syncthreads();   // everyone done reading cols

    // publish packed keys: (sortable fp32 << 32) | ~idx
#pragma unroll
    for (int j = 0; j < 12; ++j) {
        uint32_t u = __float_as_uint(val[j]);
        u = (u & 0x80000000u) ? ~u : (u | 0x80000000u);
        mbuf[r*97 + q*12 + j] = ((uint64_t)u << 32) | (uint64_t)(~(uint32_t)ids[j]);
    }
    __syncthreads();

    if (q == 0) {
        // merge 96 keys -> global fp32 top-12
        uint64_t kv[12];
#pragma unroll
        for (int j = 0; j < 12; ++j) kv[j] = 0ull;
        for (int i = 0; i < 96; ++i) {
            uint64_t k = mbuf[r*97 + i];
            if (k > kv[11]) insert12_u64(kv, k);
        }

        // raw row (exact inputs) for fp64 re-rank
        const float* rawp = xfT + ((size_t)b * TT + t) * CC;
#pragma unroll
        for (int c = 0; c < CC; c += 4) {
            float4 f = *(const float4*)(rawp + c);
            rv[c] = f.x; rv[c+1] = f.y; rv[c+2] = f.z; rv[c+3] = f.w;
        }

        // fp64 re-rank of 12 candidates -> exact top-8 (desc, idx asc on ties)
        double v8[8]; int i8[8];
#pragma unroll
        for (int j = 0; j < 8; ++j) { v8[j] = -1.0e300; i8[j] = 0x7FFFFFFF; }
        for (int jc = 0; jc < 12; ++jc) {
            int idx = (int)(~(uint32_t)kv[jc]);
            const float* cp = xfT + ((size_t)b * TT + idx) * CC;
            double acc = 0.0;
#pragma unroll
            for (int c = 0; c < CC; ++c)
                acc = fma((double)rv[c], (double)cp[c], acc);
            double scr = acc * invn[(size_t)b * TT + idx];

            bool better7 = (scr > v8[7]) || (scr == v8[7] && idx < i8[7]);
            if (better7) {
#pragma unroll
                for (int j = 7; j >= 1; --j) {
                    bool up   = (scr > v8[j-1]) || (scr == v8[j-1] && idx < i8[j-1]);
                    bool here = ((scr > v8[j]) || (scr == v8[j] && idx < i8[j])) && !up;
                    v8[j] = up ? v8[j-1] : (here ? scr : v8[j]);
                    i8[j] = up ? i8[j-1] : (here ? idx : i8[j]);
                }
                bool top = (scr > v8[0]) || (scr == v8[0] && idx < i8[0]);
                if (top) { v8[0] = scr; i8[0] = idx; }
            }
        }

        int oi[9];
#pragma unroll
        for (int j = 0; j < 8; ++j) oi[j] = i8[j];
        oi[8] = t;   // self (forced 1.1 -> always member)
        for (int a = 1; a < 9; ++a) {
            int kvv = oi[a]; int jj = a - 1;
            while (jj >= 0 && oi[jj] > kvv) { oi[jj+1] = oi[jj]; --jj; }
            oi[jj+1] = kvv;
        }
        int* op = idxo + ((size_t)b * TT + t) * KK;
#pragma unroll
        for (int m = 0; m < 9; ++m) op[m] = oi[m];
    }
}

// ---------------------------------------------------------------------------
// Kernel 3: gather + conv1d(kernel=K, stride=K).
//   out[b][o][t] = sum_{k,c} W[o][c][k] * xfT[b][idx[b][t][k]][c]
// ---------------------------------------------------------------------------
__global__ __launch_bounds__(256) void gconv_kernel(
    const float* __restrict__ xfT, const int* __restrict__ idxi,
    const float* __restrict__ Wt, float* __restrict__ out)
{
    __shared__ float wl[288 * 65];
    __shared__ float ot[4][64 * 17];

    int tid = threadIdx.x;
    int b   = blockIdx.y;
    int t0  = blockIdx.x * 64;

    for (int f = tid; f < OC * 288; f += 256) {
        int o  = f / 288;
        int ck = f - o * 288;
        wl[ck * 65 + o] = Wt[f];
    }
    __syncthreads();

    int w    = tid >> 6;
    int lane = tid & 63;        // = output channel o
    int tw0  = t0 + w * 16;

    for (int i = 0; i < 16; ++i) {
        int t = tw0 + i;
        const int* ip = idxi + ((size_t)b * TT + t) * KK;
        float acc = 0.f;
#pragma unroll
        for (int k = 0; k < KK; ++k) {
            int s = __builtin_amdgcn_readfirstlane(ip[k]);
            const float* col = xfT + ((size_t)b * TT + s) * CC;
#pragma unroll
            for (int c4 = 0; c4 < CC; c4 += 4) {
                float4 xv = *(const float4*)(col + c4);
                acc = fmaf(xv.x, wl[((c4+0)*9 + k)*65 + lane], acc);
                acc = fmaf(xv.y, wl[((c4+1)*9 + k)*65 + lane], acc);
                acc = fmaf(xv.z, wl[((c4+2)*9 + k)*65 + lane], acc);
                acc = fmaf(xv.w, wl[((c4+3)*9 + k)*65 + lane], acc);
            }
        }
        ot[w][lane * 17 + i] = acc;
    }
    __syncthreads();

    for (int j = 0; j < 16; ++j) {
        int fl = j * 64 + lane;
        int o  = fl >> 4;
        int ii = fl & 15;
        out[((size_t)b * OC + o) * TT + tw0 + ii] = ot[w][o * 17 + ii];
    }
}

// ---------------------------------------------------------------------------
extern "C" void kernel_launch(void* const* d_in, const int* in_sizes, int n_in,
                              void* d_out, int out_size, void* d_ws, size_t ws_size,
                              hipStream_t stream)
{
    const float* x  = (const float*)d_in[0];   // [8][32][56][56]
    const float* Wt = (const float*)d_in[1];   // [64][32][9]
    float* out = (float*)d_out;                // [8][64][56][56]

    // workspace: xnT (fp32) | xfT (fp32) | invn (fp64) | idx (int)
    float*  xnT  = (float*)d_ws;
    float*  xfT  = xnT + (size_t)BB * TT * CC;
    double* invn = (double*)(xfT + (size_t)BB * TT * CC);
    int*    idw  = (int*)(invn + (size_t)BB * TT);

    dim3 g1((TT + 255) / 256, BB);
    norm_kernel<<<g1, 256, 0, stream>>>(x, xnT, xfT, invn);

    dim3 g2(TT / 32, BB);    // 98 x 8 = 784 blocks
    topk_kernel<<<g2, 256, 0, stream>>>(xnT, xfT, invn, idw);

    dim3 g3(TT / 64, BB);    // 49 x 8 = 392 blocks
    gconv_kernel<<<g3, 256, 0, stream>>>(xfT, idw, Wt, out);
}